// Round 11
// baseline (106.496 us; speedup 1.0000x reference)
//
#include <hip/hip_runtime.h>
#include <stdint.h>

#define N_BOX 1024
#define NUM_CLASSES 80
#define MAX_OUT 100
#define KEPT_STRIDE 128  // ints per class (512 B)

__device__ __forceinline__ void cas64(unsigned long long& a, unsigned long long& b, bool desc) {
    bool sw = desc ? (a < b) : (a > b);
    unsigned long long t = a;
    a = sw ? b : a;
    b = sw ? t : b;
}

// Phase 1: per-class key build + hybrid register/shfl bitonic sort (verified R5-R10).
// Output: sorted keys (descending) to gkeys[c*N_BOX ..]. 80 blocks x 256 threads.
__global__ __launch_bounds__(256) void sort_kernel(const float* __restrict__ scores,
                                                   unsigned long long* __restrict__ gkeys) {
    __shared__ unsigned long long keys[N_BOX];  // 8 KB
    const int c = blockIdx.x;
    const int tid = threadIdx.x;
    const int lane = tid & 63;

    const float* sc = scores + (size_t)c * N_BOX;
    float4 s4 = reinterpret_cast<const float4*>(sc)[tid];
    const int i0 = tid * 4;
    unsigned long long K[4];
    K[0] = ((unsigned long long)__float_as_uint(s4.x) << 32) | (unsigned long long)(0xFFFFFFFFu - (unsigned)(i0 + 0));
    K[1] = ((unsigned long long)__float_as_uint(s4.y) << 32) | (unsigned long long)(0xFFFFFFFFu - (unsigned)(i0 + 1));
    K[2] = ((unsigned long long)__float_as_uint(s4.z) << 32) | (unsigned long long)(0xFFFFFFFFu - (unsigned)(i0 + 2));
    K[3] = ((unsigned long long)__float_as_uint(s4.w) << 32) | (unsigned long long)(0xFFFFFFFFu - (unsigned)(i0 + 3));

    auto shfl_pass = [&](int j, bool d) {
        int xl = j >> 2;
        bool mx = (d == ((lane & xl) == 0));
#pragma unroll
        for (int t = 0; t < 4; ++t) {
            unsigned long long p = __shfl_xor(K[t], xl, 64);
            K[t] = mx ? (K[t] >= p ? K[t] : p) : (K[t] <= p ? K[t] : p);
        }
    };
    auto thread_pass = [&](bool d) {
        cas64(K[0], K[2], d); cas64(K[1], K[3], d);
        cas64(K[0], K[1], d); cas64(K[2], K[3], d);
    };
    auto lds_pass = [&](int j, bool d) {
        *reinterpret_cast<ulonglong2*>(&keys[i0])     = make_ulonglong2(K[0], K[1]);
        *reinterpret_cast<ulonglong2*>(&keys[i0 + 2]) = make_ulonglong2(K[2], K[3]);
        __syncthreads();
        int pb = i0 ^ j;
        ulonglong2 p01 = *reinterpret_cast<const ulonglong2*>(&keys[pb]);
        ulonglong2 p23 = *reinterpret_cast<const ulonglong2*>(&keys[pb + 2]);
        unsigned long long P[4] = {p01.x, p01.y, p23.x, p23.y};
        bool mx = (d == ((i0 & j) == 0));
#pragma unroll
        for (int t = 0; t < 4; ++t)
            K[t] = mx ? (K[t] >= P[t] ? K[t] : P[t]) : (K[t] <= P[t] ? K[t] : P[t]);
        __syncthreads();
    };

    cas64(K[0], K[1], true);
    cas64(K[2], K[3], false);
    { bool d = (tid & 1) == 0; thread_pass(d); }
    for (int k = 8; k <= 256; k <<= 1) {
        bool d = (tid & (k >> 2)) == 0;
        for (int j = k >> 1; j >= 4; j >>= 1) shfl_pass(j, d);
        thread_pass(d);
    }
    { bool d = (tid & 128) == 0;
      lds_pass(256, d);
      for (int j = 128; j >= 4; j >>= 1) shfl_pass(j, d);
      thread_pass(d); }
    { lds_pass(512, true); lds_pass(256, true);
      for (int j = 128; j >= 4; j >>= 1) shfl_pass(j, true);
      thread_pass(true); }

    unsigned long long* gk = gkeys + (size_t)c * N_BOX;
    *reinterpret_cast<ulonglong2*>(&gk[i0])     = make_ulonglong2(K[0], K[1]);
    *reinterpret_cast<ulonglong2*>(&gk[i0 + 2]) = make_ulonglong2(K[2], K[3]);
}

// Phase 2: greedy NMS v2 (verified R10). 80 blocks x 64 threads (one wave, no idle waves).
__global__ __launch_bounds__(64) void greedy_kernel(const float* __restrict__ boxes,
                                                    const unsigned long long* __restrict__ gkeys,
                                                    int* __restrict__ keptIdx,
                                                    unsigned int* __restrict__ counts) {
    __shared__ float4 sbox[N_BOX];              // 16 KB
    __shared__ float sarea[N_BOX];              // 4 KB
    __shared__ unsigned long long keys[N_BOX];  // 8 KB
    const int c = blockIdx.x;
    const int lane = threadIdx.x;               // 0..63

    for (int i = lane; i < N_BOX; i += 64) {
        float4 b = reinterpret_cast<const float4*>(boxes)[i];
        sbox[i] = b;
        sarea[i] = (b.z - b.x) * (b.w - b.y);
        keys[i] = gkeys[(size_t)c * N_BOX + i];
    }
    // single wave: ds/vm waits inserted by compiler; no barrier needed

    int kept = 0;
    int* outc = keptIdx + c * KEPT_STRIDE;
    float4 kbox[MAX_OUT > 0 ? 2 : 1];  // placeholder to avoid unused warnings
    (void)kbox;
    __shared__ float4 kb_s[MAX_OUT];
    __shared__ float ka_s[MAX_OUT];

    for (int base = 0; base < N_BOX && kept < MAX_OUT; base += 64) {
        unsigned long long kk = keys[base + lane];
        unsigned int hi = (unsigned int)(kk >> 32);
        unsigned int o = 0xFFFFFFFFu - (unsigned int)kk;
        bool valid = hi > 0x3F000000u;           // score > 0.5f
        if (__ballot(valid) == 0ull) break;
        float4 mb = sbox[o];
        float ma = sarea[o];
        bool alive = valid;
        for (int j = 0; j < kept; ++j) {
            float4 kb = kb_s[j];
            float ih = fminf(kb.z, mb.z) - fmaxf(kb.x, mb.x); ih = fmaxf(ih, 0.0f);
            float iw = fminf(kb.w, mb.w) - fmaxf(kb.y, mb.y); iw = fmaxf(iw, 0.0f);
            float inter = ih * iw;
            float uni = ka_s[j] + ma - inter;
            alive = alive && !((inter / uni) > 0.5f);
        }
        unsigned long long m = __ballot(alive);
        if (m == 0ull) continue;
        unsigned long long row = 0ull;
#pragma unroll 8
        for (int j = 0; j < 64; ++j) {
            unsigned int oj = (unsigned int)__shfl((int)o, j);
            float4 bj = sbox[oj];
            float aj = sarea[oj];
            float ih = fminf(bj.z, mb.z) - fmaxf(bj.x, mb.x); ih = fmaxf(ih, 0.0f);
            float iw = fminf(bj.w, mb.w) - fmaxf(bj.y, mb.y); iw = fmaxf(iw, 0.0f);
            float inter = ih * iw;
            float uni = aj + ma - inter;
            if ((inter / uni) > 0.5f) row |= 1ull << j;
        }
        unsigned long long Km = 0ull;
        int kept0 = kept;
        while (m != 0ull && kept < MAX_OUT) {
            int f = __builtin_ctzll(m);
            Km |= 1ull << f;
            ++kept;
            unsigned int rlo = (unsigned int)__builtin_amdgcn_readlane((int)(unsigned int)row, f);
            unsigned int rhi = (unsigned int)__builtin_amdgcn_readlane((int)(unsigned int)(row >> 32), f);
            unsigned long long rowf = ((unsigned long long)rhi << 32) | rlo;
            m &= ~rowf;
        }
        if ((Km >> lane) & 1ull) {
            int pos = kept0 + __popcll(Km & ((1ull << lane) - 1ull));
            outc[pos] = (int)o;
            kb_s[pos] = mb;
            ka_s[pos] = ma;
        }
    }
    if (lane == 0) counts[c] = (unsigned int)kept;
}

// Phase 3: zero output, prefix over counts, scatter (0, c, idx) packed rows (verified R7).
__global__ __launch_bounds__(256) void compact_kernel(const int* __restrict__ keptIdx,
                                                      const unsigned int* __restrict__ counts,
                                                      int* __restrict__ out) {
    int4* o4 = reinterpret_cast<int4*>(out);
    for (int i = threadIdx.x; i < (NUM_CLASSES * MAX_OUT * 3) / 4; i += 256)
        o4[i] = make_int4(0, 0, 0, 0);
    __shared__ int offs[NUM_CLASSES + 1];
    if (threadIdx.x == 0) {
        int s = 0;
        for (int c = 0; c < NUM_CLASSES; ++c) { offs[c] = s; s += (int)counts[c]; }
        offs[NUM_CLASSES] = s;
    }
    __syncthreads();
    for (int idx = threadIdx.x; idx < NUM_CLASSES * MAX_OUT; idx += 256) {
        int c = idx / MAX_OUT;
        int r = idx - c * MAX_OUT;
        int o0 = offs[c];
        if (r < offs[c + 1] - o0) {
            int o = o0 + r;
            out[o * 3 + 0] = 0;  // B == 1
            out[o * 3 + 1] = c;
            out[o * 3 + 2] = keptIdx[c * KEPT_STRIDE + r];
        }
    }
}

extern "C" void kernel_launch(void* const* d_in, const int* in_sizes, int n_in,
                              void* d_out, int out_size, void* d_ws, size_t ws_size,
                              hipStream_t stream) {
    const float* boxes = (const float*)d_in[0];   // (1, 1024, 4) f32
    const float* scores = (const float*)d_in[1];  // (1, 80, 1024) f32
    int* out = (int*)d_out;                        // (8000, 3) int32

    unsigned long long* gkeys = (unsigned long long*)d_ws;           // 80*1024*8 = 640 KB
    int* keptIdx = (int*)(gkeys + (size_t)NUM_CLASSES * N_BOX);      // 80*128 ints
    unsigned int* counts = (unsigned int*)(keptIdx + NUM_CLASSES * KEPT_STRIDE);

    sort_kernel<<<NUM_CLASSES, 256, 0, stream>>>(scores, gkeys);
    greedy_kernel<<<NUM_CLASSES, 64, 0, stream>>>(boxes, gkeys, keptIdx, counts);
    compact_kernel<<<1, 256, 0, stream>>>(keptIdx, counts, out);
}

// Round 12
// 105.536 us; speedup vs baseline: 1.0091x; 1.0091x over previous
//
#include <hip/hip_runtime.h>
#include <stdint.h>

#define N_BOX 1024
#define NUM_CLASSES 80
#define MAX_OUT 100
#define KEPT_STRIDE 128  // ints per class (512 B) — no cross-XCD false sharing
#define WS_POISON 0xAAAAAAAAu
#define PRE_W 12         // windows with precomputed 64x64 suppression matrices

__device__ __forceinline__ void cas64(unsigned long long& a, unsigned long long& b, bool desc) {
    bool sw = desc ? (a < b) : (a > b);
    unsigned long long t = a;
    a = sw ? b : a;
    b = sw ? t : b;
}

// Single fused dispatch, 80 blocks (one class each) — R10 structure (best total) plus:
// in-window 64x64 IoU matrices for the first PRE_W windows are precomputed by ALL 4
// waves in parallel (they depend only on sorted keys), removing the 64-iter IoU loop
// from wave 0's serial greedy path. Greedy/resolution/publish/poll identical to R10.
__global__ __launch_bounds__(256) void nms_fused(const float* __restrict__ boxes,
                                                 const float* __restrict__ scores,
                                                 int* __restrict__ keptIdx,
                                                 unsigned int* __restrict__ counts,
                                                 unsigned int* __restrict__ ready,
                                                 int* __restrict__ out) {
    __shared__ float4 sbox[N_BOX];              // 16 KB  [y1,x1,y2,x2]
    __shared__ float sarea[N_BOX];              // 4 KB
    __shared__ unsigned long long keys[N_BOX];  // 8 KB
    __shared__ unsigned long long wmat[PRE_W * 64];  // 6 KB: per-window suppression rows
    __shared__ float4 kbox[MAX_OUT];            // kept boxes
    __shared__ float karea[MAX_OUT];
    __shared__ int scnt[NUM_CLASSES];
    const int c = blockIdx.x;
    const int tid = threadIdx.x;
    const int lane = tid & 63;
    const int wv = tid >> 6;

    for (int i = tid; i < N_BOX; i += 256) {
        float4 b = reinterpret_cast<const float4*>(boxes)[i];
        sbox[i] = b;
        sarea[i] = (b.z - b.x) * (b.w - b.y);
    }

    // Keys: (score_bits<<32) | (0xFFFFFFFF - idx); descending == stable argsort(-scores).
    const float* sc = scores + (size_t)c * N_BOX;
    float4 s4 = reinterpret_cast<const float4*>(sc)[tid];
    const int i0 = tid * 4;
    unsigned long long K[4];
    K[0] = ((unsigned long long)__float_as_uint(s4.x) << 32) | (unsigned long long)(0xFFFFFFFFu - (unsigned)(i0 + 0));
    K[1] = ((unsigned long long)__float_as_uint(s4.y) << 32) | (unsigned long long)(0xFFFFFFFFu - (unsigned)(i0 + 1));
    K[2] = ((unsigned long long)__float_as_uint(s4.z) << 32) | (unsigned long long)(0xFFFFFFFFu - (unsigned)(i0 + 2));
    K[3] = ((unsigned long long)__float_as_uint(s4.w) << 32) | (unsigned long long)(0xFFFFFFFFu - (unsigned)(i0 + 3));

    auto shfl_pass = [&](int j, bool d) {  // element-xor j>=4 -> lane-xor j/4 within wave
        int xl = j >> 2;
        bool mx = (d == ((lane & xl) == 0));
#pragma unroll
        for (int t = 0; t < 4; ++t) {
            unsigned long long p = __shfl_xor(K[t], xl, 64);
            K[t] = mx ? (K[t] >= p ? K[t] : p) : (K[t] <= p ? K[t] : p);
        }
    };
    auto thread_pass = [&](bool d) {
        cas64(K[0], K[2], d); cas64(K[1], K[3], d);
        cas64(K[0], K[1], d); cas64(K[2], K[3], d);
    };
    auto lds_pass = [&](int j, bool d) {  // cross-wave via LDS
        *reinterpret_cast<ulonglong2*>(&keys[i0])     = make_ulonglong2(K[0], K[1]);
        *reinterpret_cast<ulonglong2*>(&keys[i0 + 2]) = make_ulonglong2(K[2], K[3]);
        __syncthreads();
        int pb = i0 ^ j;
        ulonglong2 p01 = *reinterpret_cast<const ulonglong2*>(&keys[pb]);
        ulonglong2 p23 = *reinterpret_cast<const ulonglong2*>(&keys[pb + 2]);
        unsigned long long P[4] = {p01.x, p01.y, p23.x, p23.y};
        bool mx = (d == ((i0 & j) == 0));
#pragma unroll
        for (int t = 0; t < 4; ++t)
            K[t] = mx ? (K[t] >= P[t] ? K[t] : P[t]) : (K[t] <= P[t] ? K[t] : P[t]);
        __syncthreads();
    };

    cas64(K[0], K[1], true);   // k=2
    cas64(K[2], K[3], false);
    { bool d = (tid & 1) == 0; thread_pass(d); }  // k=4
    for (int k = 8; k <= 256; k <<= 1) {
        bool d = (tid & (k >> 2)) == 0;
        for (int j = k >> 1; j >= 4; j >>= 1) shfl_pass(j, d);
        thread_pass(d);
    }
    { bool d = (tid & 128) == 0;  // k=512
      lds_pass(256, d);
      for (int j = 128; j >= 4; j >>= 1) shfl_pass(j, d);
      thread_pass(d); }
    {                             // k=1024 (final, all desc)
      lds_pass(512, true); lds_pass(256, true);
      for (int j = 128; j >= 4; j >>= 1) shfl_pass(j, true);
      thread_pass(true); }
    *reinterpret_cast<ulonglong2*>(&keys[i0])     = make_ulonglong2(K[0], K[1]);
    *reinterpret_cast<ulonglong2*>(&keys[i0 + 2]) = make_ulonglong2(K[2], K[3]);
    __syncthreads();  // keys published; sbox/sarea staging complete

    // --- Parallel precompute of in-window 64x64 suppression matrices (all 4 waves) ---
    // Row for sorted slot (w*64+lane): bit j = IoU(me, slot w*64+j) > 0.5.
    // Depends only on sorted keys. Garbage rows for invalid slots are harmless
    // (resolution masks by the alive ballot). Self-bit is set (IoU = 1).
    for (int w = wv; w < PRE_W; w += 4) {
        unsigned long long kk = keys[w * 64 + lane];
        unsigned int o = 0xFFFFFFFFu - (unsigned int)kk;
        float4 mb = sbox[o];
        float ma = sarea[o];
        unsigned long long row = 0ull;
#pragma unroll 8
        for (int j = 0; j < 64; ++j) {
            unsigned long long kj = keys[w * 64 + j];   // uniform LDS read (broadcast)
            unsigned int oj = 0xFFFFFFFFu - (unsigned int)kj;
            float4 bj = sbox[oj];
            float aj = sarea[oj];
            float ih = fminf(bj.z, mb.z) - fmaxf(bj.x, mb.x); ih = fmaxf(ih, 0.0f);
            float iw = fminf(bj.w, mb.w) - fmaxf(bj.y, mb.y); iw = fmaxf(iw, 0.0f);
            float inter = ih * iw;
            float uni = aj + ma - inter;
            if ((inter / uni) > 0.5f) row |= 1ull << j;
        }
        wmat[w * 64 + lane] = row;
    }
    __syncthreads();

    // --- Greedy NMS on wave 0 (R10-verified; matrix loop replaced by LDS row load) ---
    if (tid < 64) {
        int kept = 0;
        int* outc = keptIdx + c * KEPT_STRIDE;
        for (int base = 0; base < N_BOX && kept < MAX_OUT; base += 64) {
            unsigned long long kk = keys[base + lane];
            unsigned int hi = (unsigned int)(kk >> 32);
            unsigned int o = 0xFFFFFFFFu - (unsigned int)kk;
            bool valid = hi > 0x3F000000u;           // score > 0.5f (nonneg floats)
            if (__ballot(valid) == 0ull) break;      // sorted: nothing left
            float4 mb = sbox[o];
            float ma = sarea[o];
            // Cross-window: test my candidate vs kept list (lane-parallel, pipelines).
            bool alive = valid;
            for (int j = 0; j < kept; ++j) {
                float4 kb = kbox[j];
                float ih = fminf(kb.z, mb.z) - fmaxf(kb.x, mb.x); ih = fmaxf(ih, 0.0f);
                float iw = fminf(kb.w, mb.w) - fmaxf(kb.y, mb.y); iw = fmaxf(iw, 0.0f);
                float inter = ih * iw;
                float uni = karea[j] + ma - inter;   // ref op order
                alive = alive && !((inter / uni) > 0.5f);
            }
            unsigned long long m = __ballot(alive);
            if (m == 0ull) continue;
            // In-window suppression row: precomputed (windows < PRE_W) or inline.
            unsigned long long row;
            int w = base >> 6;
            if (w < PRE_W) {
                row = wmat[base + lane];             // one LDS read, conflict-free
            } else {
                row = 0ull;
#pragma unroll 8
                for (int j = 0; j < 64; ++j) {
                    unsigned int oj = (unsigned int)__shfl((int)o, j);
                    float4 bj = sbox[oj];
                    float aj = sarea[oj];
                    float ih = fminf(bj.z, mb.z) - fmaxf(bj.x, mb.x); ih = fmaxf(ih, 0.0f);
                    float iw = fminf(bj.w, mb.w) - fmaxf(bj.y, mb.y); iw = fmaxf(iw, 0.0f);
                    float inter = ih * iw;
                    float uni = aj + ma - inter;
                    if ((inter / uni) > 0.5f) row |= 1ull << j;
                }
            }
            // Scalar resolution: per kept box ~ ctz + 2 dynamic v_readlane + andn2.
            unsigned long long Km = 0ull;
            int kept0 = kept;
            while (m != 0ull && kept < MAX_OUT) {
                int f = __builtin_ctzll(m);          // lowest lane = best score
                Km |= 1ull << f;
                ++kept;
                unsigned int rlo = (unsigned int)__builtin_amdgcn_readlane((int)(unsigned int)row, f);
                unsigned int rhi = (unsigned int)__builtin_amdgcn_readlane((int)(unsigned int)(row >> 32), f);
                unsigned long long rowf = ((unsigned long long)rhi << 32) | rlo;
                m &= ~rowf;                          // clears f (self-bit) + all it suppresses
            }
            // Parallel append of this window's kept boxes in sorted (lane) order.
            if ((Km >> lane) & 1ull) {
                int pos = kept0 + __popcll(Km & ((1ull << lane) - 1ull));
                outc[pos] = (int)o;
                kbox[pos] = mb;
                karea[pos] = ma;
            }
        }
        if (lane == 0) {
            __hip_atomic_store(&counts[c], (unsigned int)kept,
                               __ATOMIC_RELEASE, __HIP_MEMORY_SCOPE_SYSTEM);
            __hip_atomic_fetch_add(ready, 1u,
                                   __ATOMIC_RELEASE, __HIP_MEMORY_SCOPE_SYSTEM);
        }
    }

    if (c != 0) return;  // blocks 1..79 done

    // --- Block 0 epilogue (R9/R10-proven) ---
    if (tid == 64) {
        // RMW poll at the coherence point — cannot read stale L2. Poison target:
        const unsigned int target = WS_POISON + (unsigned int)NUM_CLASSES;
        unsigned int v;
        do {
            v = __hip_atomic_fetch_add(ready, 0u, __ATOMIC_ACQUIRE, __HIP_MEMORY_SCOPE_SYSTEM);
        } while (v != target);
    } else if (tid >= 144) {
        int4* o4 = reinterpret_cast<int4*>(out);
        for (int i = tid - 144; i < (NUM_CLASSES * MAX_OUT * 3) / 4; i += 112)
            o4[i] = make_int4(0, 0, 0, 0);
    }
    __syncthreads();  // greedy done, all 80 publishes observed, out zeroed

    if (tid < NUM_CLASSES)
        scnt[tid] = (int)__hip_atomic_load(&counts[tid], __ATOMIC_RELAXED,
                                           __HIP_MEMORY_SCOPE_SYSTEM);
    __syncthreads();

    // Inclusive Hillis-Steele scan over 80 counts in LDS.
    for (int d = 1; d < NUM_CLASSES; d <<= 1) {
        int v = 0;
        if (tid < NUM_CLASSES) {
            v = scnt[tid];
            if (tid >= d) v += scnt[tid - d];
        }
        __syncthreads();
        if (tid < NUM_CLASSES) scnt[tid] = v;
        __syncthreads();
    }

    // Scatter rows (0, c, idx) packed by (class, rank).
    for (int idx = tid; idx < NUM_CLASSES * MAX_OUT; idx += 256) {
        int c2 = idx / MAX_OUT;
        int r = idx - c2 * MAX_OUT;
        int excl = (c2 == 0) ? 0 : scnt[c2 - 1];
        if (r < scnt[c2] - excl) {
            int o = excl + r;
            out[o * 3 + 0] = 0;  // B == 1
            out[o * 3 + 1] = c2;
            out[o * 3 + 2] = keptIdx[c2 * KEPT_STRIDE + r];
        }
    }
}

extern "C" void kernel_launch(void* const* d_in, const int* in_sizes, int n_in,
                              void* d_out, int out_size, void* d_ws, size_t ws_size,
                              hipStream_t stream) {
    const float* boxes = (const float*)d_in[0];   // (1, 1024, 4) f32
    const float* scores = (const float*)d_in[1];  // (1, 80, 1024) f32
    int* out = (int*)d_out;                        // (8000, 3) int32

    int* keptIdx = (int*)d_ws;                                     // 80*128 ints
    unsigned int* counts = (unsigned int*)(keptIdx + NUM_CLASSES * KEPT_STRIDE);
    unsigned int* ready = counts + 128;            // own 512B-aligned region

    nms_fused<<<NUM_CLASSES, 256, 0, stream>>>(boxes, scores, keptIdx, counts, ready, out);
}